// Round 8
// baseline (167.842 us; speedup 1.0000x reference)
//
#include <hip/hip_runtime.h>

// Problem constants
#define NB 32768
#define NT 16
#define NV 32001   // V+1
#define NE 32
#define NTAGS 64

typedef __attribute__((ext_vector_type(8))) short short8;   // 8 bf16 (4 VGPR)
typedef __attribute__((ext_vector_type(4))) float f4;       // MFMA acc

#define MFMA16(a, b, c) __builtin_amdgcn_mfma_f32_16x16x32_bf16(a, b, c, 0, 0, 0)
// DS ops are in-order within a wave -> compiler-only fence suffices for same-wave LDS RAW
#define CFENCE() asm volatile("" ::: "memory")
#define LDSSYNC() asm volatile("s_waitcnt lgkmcnt(0)" ::: "memory")

__device__ __forceinline__ float sigm_(float x) {
    return __builtin_amdgcn_rcpf(1.0f + __expf(-x));
}
__device__ __forceinline__ float tanh2_(float x) {  // 2*sigm(2x)-1
    float e = __expf(-2.0f * x);
    return fmaf(2.0f, __builtin_amdgcn_rcpf(1.0f + e), -1.0f);
}
__device__ __forceinline__ short f2bf(float x) {  // RNE float->bf16 bits
    union { float f; unsigned u; } v; v.f = x;
    unsigned r = v.u + 0x7fffu + ((v.u >> 16) & 1u);
    return (short)(r >> 16);
}

// ---------------- K1: classify (32 slabs, no atomics) + emb->bf16 + weight pack ----------------
__global__ __launch_bounds__(1024) void classify_prep(
    const int* __restrict__ s, const float* __restrict__ emb,
    const float* __restrict__ Wih, const float* __restrict__ Whh,
    const float* __restrict__ bih, const float* __restrict__ bhh,
    const float* __restrict__ Wc, const float* __restrict__ Wt,
    short* __restrict__ embH, short* __restrict__ wpack, short* __restrict__ wc1,
    short* __restrict__ wc2, short* __restrict__ wth, float* __restrict__ bsum,
    int* __restrict__ cH, int* __restrict__ listH, int* __restrict__ listL) {
    __shared__ int wbH[16], wbL[16];
    const int tid = threadIdx.x, b = blockIdx.x;
    if (b < 32) {
        const int row = b * 1024 + tid;
        const bool heavy = s[row] >= 4;
        unsigned long long mk = __ballot(heavy);
        const int wv = tid >> 6, ln = tid & 63;
        if (ln == 0) wbH[wv] = __popcll(mk);
        __syncthreads();
        if (tid == 0) {
            int tH = 0, tL = 0;
#pragma unroll
            for (int i = 0; i < 16; ++i) {
                int ch = wbH[i];
                wbH[i] = tH; wbL[i] = tL;
                tH += ch; tL += 64 - ch;
            }
            cH[b] = tH;
        }
        __syncthreads();
        unsigned long long ltm = (1ull << ln) - 1ull;
        if (heavy) listH[b * 1024 + wbH[wv] + __popcll(mk & ltm)] = row;
        else       listL[b * 1024 + wbL[wv] + __popcll((~mk) & ltm)] = row;
    }
    // emb -> bf16 (striped over all 256 blocks)
    for (int i = b * 1024 + tid; i < NV * NE; i += 262144) embH[i] = f2bf(emb[i]);
    if (b == 32) {  // weight pack
        for (int t = tid; t < 18432; t += 1024) {
            int r = t / 72, c = t % 72;
            wpack[t] = f2bf(c < 64 ? Whh[r * 64 + c] : 0.f);
        }
        for (int t = tid; t < 10240; t += 1024) {
            int r = t / 40, c = t % 40;
            wpack[18432 + t] = f2bf(c < 32 ? Wih[r * 32 + c] : 0.f);
        }
        if (tid < 1024) { int r = tid >> 5, c = tid & 31; wc1[tid] = f2bf(Wc[r * 96 + c]); }
        for (int t = tid; t < 2048; t += 1024) {
            int r = t >> 6, c = t & 63;
            wc2[t] = f2bf(Wc[r * 96 + 32 + c]);
        }
        for (int t = tid; t < 2048; t += 1024) {
            int r = t >> 5, c = t & 31;
            wth[t] = f2bf(Wt[r * 32 + c]);
        }
        if (tid < 256) bsum[tid] = bih[tid] + bhh[tid];
    }
}

// ---------------- K2: fused main — heavy (4 rows/wave, MFMA) + light (16 rows/iter, MFMA) --------
__global__ __launch_bounds__(256, 3) void main_fused(
    const int* __restrict__ x, const float* __restrict__ emb,
    const float* __restrict__ h0, const float* __restrict__ c0,
    const float* __restrict__ Wc, const float* __restrict__ bc,
    const float* __restrict__ Wt, const float* __restrict__ bt,
    const float* __restrict__ bsum,
    const short* __restrict__ wpack, const short* __restrict__ wc1,
    const short* __restrict__ wc2, const short* __restrict__ wth,
    const short* __restrict__ embH, const int* __restrict__ cH,
    const int* __restrict__ listH, const int* __restrict__ listL,
    float* __restrict__ out) {
    __shared__ __align__(16) short sWhh[18432];      // 36 KB [256][72] bf16 (FULL: 2304 uint4)
    __shared__ __align__(16) short sHA[4][16 * 72];  // per-wave h, A-frag layout (bf16)
    __shared__ __align__(16) short sCmb[4][16 * 40]; // per-wave comb[(node*4+row)][40] / light comb
    __shared__ __align__(16) short sC4[4][4 * 40];   // per-wave comb4[row][40]

    const int tid = threadIdx.x, wave = tid >> 6, lane = tid & 63;
    const int q = lane >> 4, n = lane & 15;
    const int NW = gridDim.x * 4;  // 3072
    const int gw = blockIdx.x * 4 + wave;

    // 32-slab prefix scan (per wave, shfl) — before staging so we can skip it
    int cs = (lane < 32) ? cH[lane] : 0;
    int v = cs;
#pragma unroll
    for (int o = 1; o < 32; o <<= 1) { int t2 = __shfl_up(v, o); if (lane >= o) v += t2; }
    const int vIncl = v, vExcl = v - cs;
    const int nH = __shfl(vIncl, 31);
    const int nL = NB - nH;
    const int liIncl = (lane + 1) * 1024 - vIncl;  // light prefixes (lane<32)
    const int liExcl = lane * 1024 - vExcl;
    const int nHW = (nH + 3) >> 2;                 // heavy wave count

    if ((int)blockIdx.x * 4 < nHW) {  // block-uniform: only heavy blocks stage Whh
        for (int i = tid; i < 2304; i += 256)
            ((uint4*)sWhh)[i] = ((const uint4*)wpack)[i];
        __syncthreads();
    }

    if (gw < nHW) {
        short* hA = sHA[wave];
        short* cmb = sCmb[wave];
        short* c4 = sC4[wave];
        const short* wihG = wpack + 18432;

        // loop-invariant Wih fragments in registers (64 VGPR) — no per-step global loads
        short8 wihR[16];
#pragma unroll
        for (int tl = 0; tl < 16; ++tl)
            wihR[tl] = *(const short8*)&wihG[(tl * 16 + n) * 40 + q * 8];

        float bias16[16];
#pragma unroll
        for (int tl = 0; tl < 16; ++tl) bias16[tl] = bsum[tl * 16 + n];
        float bc2[2] = {bc[n], bc[16 + n]};
        float bt4[4] = {bt[n], bt[16 + n], bt[32 + n], bt[48 + n]};
        float c0v[4]; short h0b[4];
#pragma unroll
        for (int u = 0; u < 4; ++u) { c0v[u] = c0[u * 16 + n]; h0b[u] = f2bf(h0[u * 16 + n]); }

        const f4 zero4 = {0.f, 0.f, 0.f, 0.f};
        f4 acc[16];
        float cst[4][4];

        auto initSt = [&]() {
#pragma unroll
            for (int u = 0; u < 4; ++u) {
                short hb = h0b[u];
#pragma unroll
                for (int r = 0; r < 4; ++r) {
                    cst[r][u] = c0v[u];
                    hA[(q * 4 + r) * 72 + u * 16 + n] = hb;
                }
            }
            CFENCE();
        };
        auto doStep = [&](short8 aP, bool doRelu) {
            short8 ah0 = *(const short8*)&hA[n * 72 + q * 8];
            short8 ah1 = *(const short8*)&hA[n * 72 + 32 + q * 8];
#pragma unroll
            for (int tl = 0; tl < 16; ++tl) acc[tl] = MFMA16(aP, wihR[tl], zero4);
#pragma unroll
            for (int tl = 0; tl < 16; ++tl) {
                const short* rbp = &sWhh[(tl * 16 + n) * 72 + q * 8];
                f4 t0 = acc[tl];
                t0 = MFMA16(ah0, *(const short8*)rbp, t0);
                t0 = MFMA16(ah1, *(const short8*)(rbp + 32), t0);
                acc[tl] = t0;
            }
            CFENCE();
#pragma unroll
            for (int u = 0; u < 4; ++u)
#pragma unroll
                for (int r = 0; r < 4; ++r) {
                    float ip = acc[u][r] + bias16[u];
                    float fp = acc[4 + u][r] + bias16[4 + u];
                    float gp = acc[8 + u][r] + bias16[8 + u];
                    float op = acc[12 + u][r] + bias16[12 + u];
                    float cc = fmaf(sigm_(fp), cst[r][u], sigm_(ip) * tanh2_(gp));
                    cst[r][u] = cc;
                    float hh = sigm_(op) * tanh2_(cc);
                    if (doRelu) hh = fmaxf(hh, 0.f);
                    hA[(q * 4 + r) * 72 + u * 16 + n] = f2bf(hh);
                }
            CFENCE();
        };
        // comb = relu([root,last]@Wc^T+bc) for 16 units; D unit m=q*4+r
        auto combMM = [&](short8 aroot, short* dst, int strideSel) {
            short8 lh0 = *(const short8*)&hA[n * 72 + q * 8];
            short8 lh1 = *(const short8*)&hA[n * 72 + 32 + q * 8];
#pragma unroll
            for (int tl2 = 0; tl2 < 2; ++tl2) {
                float bv = bc2[tl2];
                f4 t0 = {bv, bv, bv, bv};
                short8 b1 = *(const short8*)&wc1[(tl2 * 16 + n) * 32 + q * 8];
                t0 = MFMA16(aroot, b1, t0);
                const short* rbp = &wc2[(tl2 * 16 + n) * 64 + q * 8];
                t0 = MFMA16(lh0, *(const short8*)rbp, t0);
                t0 = MFMA16(lh1, *(const short8*)(rbp + 32), t0);
#pragma unroll
                for (int r = 0; r < 4; ++r) {
                    int ui = strideSel ? (q * 4 + r) : r;  // phase2: quads duplicate rows
                    dst[ui * 40 + tl2 * 16 + n] = f2bf(fmaxf(t0[r], 0.f));
                }
            }
            CFENCE();
        };

#pragma unroll 1
        for (int it = gw; it * 4 < nH; it += NW) {
            const int base = it * 4;
            // row of this lane's quad (uniform within quad)
            int idxq = min(base + q, nH - 1);
            int sl = 0;
#pragma unroll
            for (int b2 = 0; b2 < 32; ++b2) sl += (__shfl(vIncl, b2) <= idxq) ? 1 : 0;
            const int row = listH[sl * 1024 + idxq - __shfl(vExcl, sl)];
            const int tokAll = x[row * 16 + n];  // lane (q,n) holds x[row_q][n]
            const int liBase = (n & 3) * 16 + (n >> 2) * 4;  // unit n: row n&3, node n>>2

            // ---- phase 1: 4 rows x 4 nodes in the 16 units, 4 steps ----
            initSt();
            int tok = __shfl(tokAll, liBase);
            short8 aNext = *(const short8*)&embH[tok * 32 + q * 8];
            const short8 aRoot = aNext;
#pragma unroll 1
            for (int t = 0; t < 4; ++t) {
                short8 aP = aNext;
                if (t < 3) {
                    int tk2 = __shfl(tokAll, liBase + t + 1);
                    aNext = *(const short8*)&embH[tk2 * 32 + q * 8];
                }
                doStep(aP, t == 3);  // step 3 writes relu(h) = "last"
            }
            combMM(aRoot, cmb, 1);   // cmb[(node*4+row)][40]

            // ---- phase 2: node 4 (children = comb_0..3), rows duplicated x4 ----
            initSt();
            int tokR = __shfl(tokAll, (n & 3) * 16);
            short8 aR4 = *(const short8*)&embH[tokR * 32 + q * 8];
#pragma unroll 1
            for (int t = 0; t < 4; ++t) {
                short8 aC = *(const short8*)&cmb[(t * 4 + (n & 3)) * 40 + q * 8];
                doStep(aC, t == 3);
            }
            combMM(aR4, c4, 0);      // c4[row][40] (4 quads write identical)

            // ---- phase 3: logits + log_softmax for 4 rows ----
            short8 cA = *(const short8*)&c4[(n & 3) * 40 + q * 8];
            f4 a3[4];
#pragma unroll
            for (int tl3 = 0; tl3 < 4; ++tl3) {
                float bv = bt4[tl3];
                f4 t0 = {bv, bv, bv, bv};
                short8 bW = *(const short8*)&wth[(tl3 * 16 + n) * 32 + q * 8];
                a3[tl3] = MFMA16(cA, bW, t0);
            }
#pragma unroll
            for (int r = 0; r < 4; ++r) {
                float l0 = a3[0][r], l1 = a3[1][r], l2 = a3[2][r], l3 = a3[3][r];
                float mx = fmaxf(fmaxf(l0, l1), fmaxf(l2, l3));
#pragma unroll
                for (int o2 = 8; o2; o2 >>= 1) mx = fmaxf(mx, __shfl_xor(mx, o2));
                float sm = __expf(l0 - mx) + __expf(l1 - mx) +
                           __expf(l2 - mx) + __expf(l3 - mx);
#pragma unroll
                for (int o2 = 8; o2; o2 >>= 1) sm += __shfl_xor(sm, o2);
                float lse = mx + __logf(sm);
                if (q == r && base + r < nH) {  // quad r owns row r
                    out[row * 64 + n] = l0 - lse;
                    out[row * 64 + 16 + n] = l1 - lse;
                    out[row * 64 + 32 + n] = l2 - lse;
                    out[row * 64 + 48 + n] = l3 - lse;
                }
            }
        }
    }

    // ---- light rows: 16 rows/iteration via MFMA (comb: 2 MFMA, logits: 4 MFMA) ----
    // Assigned in REVERSE wave order so pure-light waves complement heavy waves.
    if (nL > 0) {
        short* cmbL = sCmb[wave];  // reused (heavy phase done for this wave)
        f4 bcV[2], btV[4];
#pragma unroll
        for (int t = 0; t < 2; ++t) { float bv = bc[t * 16 + n]; bcV[t] = f4{bv, bv, bv, bv}; }
#pragma unroll
        for (int t = 0; t < 4; ++t) { float bv = bt[t * 16 + n]; btV[t] = f4{bv, bv, bv, bv}; }
        const int lgw = NW - 1 - gw;
#pragma unroll 1
        for (int base = lgw * 16; base < nL; base += NW * 16) {
            int idx = min(base + lane, nL - 1);  // lane i -> light index base+i
            int sl = 0;
#pragma unroll
            for (int b2 = 0; b2 < 32; ++b2) sl += (__shfl(liIncl, b2) <= idx) ? 1 : 0;
            const int lrow = listL[sl * 1024 + idx - __shfl(liExcl, sl)];
            const int ltok = x[lrow * 16];
            short8 aE = *(const short8*)&embH[__shfl(ltok, n) * 32 + q * 8];
            // comb = relu(emb @ Wc1^T + bc) -> LDS [16][40]
#pragma unroll
            for (int tl2 = 0; tl2 < 2; ++tl2) {
                short8 b1 = *(const short8*)&wc1[(tl2 * 16 + n) * 32 + q * 8];
                f4 t0 = MFMA16(aE, b1, bcV[tl2]);
#pragma unroll
                for (int r = 0; r < 4; ++r)
                    cmbL[(q * 4 + r) * 40 + tl2 * 16 + n] = f2bf(fmaxf(t0[r], 0.f));
            }
            CFENCE();
            // logits = comb @ Wt^T + bt
            short8 cA = *(const short8*)&cmbL[n * 40 + q * 8];
            f4 a3[4];
#pragma unroll
            for (int tl3 = 0; tl3 < 4; ++tl3) {
                short8 bW = *(const short8*)&wth[(tl3 * 16 + n) * 32 + q * 8];
                a3[tl3] = MFMA16(cA, bW, btV[tl3]);
            }
#pragma unroll
            for (int r = 0; r < 4; ++r) {  // row m = q*4+r (all 16 distinct)
                float l0 = a3[0][r], l1 = a3[1][r], l2 = a3[2][r], l3 = a3[3][r];
                float mx = fmaxf(fmaxf(l0, l1), fmaxf(l2, l3));
#pragma unroll
                for (int o2 = 8; o2; o2 >>= 1) mx = fmaxf(mx, __shfl_xor(mx, o2));
                float sm = __expf(l0 - mx) + __expf(l1 - mx) +
                           __expf(l2 - mx) + __expf(l3 - mx);
#pragma unroll
                for (int o2 = 8; o2; o2 >>= 1) sm += __shfl_xor(sm, o2);
                float lse = mx + __logf(sm);
                int rowO = __shfl(lrow, q * 4 + r);
                if (base + q * 4 + r < nL) {
                    out[rowO * 64 + n] = l0 - lse;
                    out[rowO * 64 + 16 + n] = l1 - lse;
                    out[rowO * 64 + 32 + n] = l2 - lse;
                    out[rowO * 64 + 48 + n] = l3 - lse;
                }
            }
            CFENCE();
        }
    }
}

// ---------------- fallback (small ws): monolithic fp32 kernel ----------------
__global__ __launch_bounds__(512) void tagger_fallback(
    const int* __restrict__ x, const int* __restrict__ s, const float* __restrict__ emb,
    const float* __restrict__ Wih, const float* __restrict__ Whh,
    const float* __restrict__ bih, const float* __restrict__ bhh,
    const float* __restrict__ h0, const float* __restrict__ c0,
    const float* __restrict__ Wc, const float* __restrict__ bc,
    const float* __restrict__ Wt, const float* __restrict__ bt,
    float* __restrict__ out) {
    __shared__ float4 WhhP[4096];
    __shared__ float combBuf[8][128];
    for (int i = threadIdx.x; i < 4096; i += 512) {
        int k = i & 63, jj = i >> 6;
        WhhP[k * 64 + jj] = make_float4(Whh[jj * 64 + k], Whh[(jj + 64) * 64 + k],
                                        Whh[(jj + 128) * 64 + k], Whh[(jj + 192) * 64 + k]);
    }
    __syncthreads();
    const int wave = threadIdx.x >> 6, j = threadIdx.x & 63, jm = j & 31;
    const int b = blockIdx.x * 8 + wave;
    const int sv = s[b];
    const int* xb = x + b * NT;
    const float bcj = bc[jm];
    auto rc_val = [&](int tok) -> float {
        float r = 0.f;
#pragma unroll
        for (int k = 0; k < 32; ++k) r = fmaf(emb[tok * NE + k], Wc[jm * 96 + k], r);
        return r;
    };
    float comb4;
    if (sv >= 4) {
        const float h0j = h0[j], c0j = c0[j];
        float4 bsj = make_float4(bih[j] + bhh[j], bih[j + 64] + bhh[j + 64],
                                 bih[j + 128] + bhh[j + 128], bih[j + 192] + bhh[j + 192]);
#pragma unroll 1
        for (int node = 0; node < 4; ++node) {
            float h = h0j, c = c0j;
#pragma unroll 1
            for (int t = 0; t < 4; ++t) {
                int tok = xb[node * 4 + t];
                float4 p = bsj;
#pragma unroll
                for (int k = 0; k < 32; ++k) {
                    float e = emb[tok * NE + k];
                    p.x = fmaf(e, Wih[j * 32 + k], p.x);
                    p.y = fmaf(e, Wih[(j + 64) * 32 + k], p.y);
                    p.z = fmaf(e, Wih[(j + 128) * 32 + k], p.z);
                    p.w = fmaf(e, Wih[(j + 192) * 32 + k], p.w);
                }
                float4 a = make_float4(0.f, 0.f, 0.f, 0.f);
#pragma unroll
                for (int k = 0; k < 64; ++k) {
                    float hk = __shfl(h, k);
                    float4 w = WhhP[k * 64 + j];
                    a.x = fmaf(hk, w.x, a.x); a.y = fmaf(hk, w.y, a.y);
                    a.z = fmaf(hk, w.z, a.z); a.w = fmaf(hk, w.w, a.w);
                }
                a.x += p.x; a.y += p.y; a.z += p.z; a.w += p.w;
                float ig = sigm_(a.x), fg = sigm_(a.y), gg = tanh2_(a.z), og = sigm_(a.w);
                c = fmaf(fg, c, ig * gg);
                h = og * tanh2_(c);
            }
            float last = fmaxf(h, 0.f);
            float acc = rc_val(xb[node * 4]) + bcj;
#pragma unroll
            for (int k = 0; k < 64; ++k)
                acc = fmaf(__shfl(last, k), Wc[jm * 96 + 32 + k], acc);
            if (j < 32) combBuf[wave][node * 32 + j] = fmaxf(acc, 0.f);
        }
        LDSSYNC();
        float h = h0j, c = c0j;
#pragma unroll 1
        for (int t = 0; t < 4; ++t) {
            float4 a = make_float4(0.f, 0.f, 0.f, 0.f);
#pragma unroll
            for (int k = 0; k < 32; ++k) {
                float ck = combBuf[wave][t * 32 + k];
                a.x = fmaf(ck, Wih[j * 32 + k], a.x);
                a.y = fmaf(ck, Wih[(j + 64) * 32 + k], a.y);
                a.z = fmaf(ck, Wih[(j + 128) * 32 + k], a.z);
                a.w = fmaf(ck, Wih[(j + 192) * 32 + k], a.w);
            }
#pragma unroll
            for (int k = 0; k < 64; ++k) {
                float hk = __shfl(h, k);
                float4 w = WhhP[k * 64 + j];
                a.x = fmaf(hk, w.x, a.x); a.y = fmaf(hk, w.y, a.y);
                a.z = fmaf(hk, w.z, a.z); a.w = fmaf(hk, w.w, a.w);
            }
            a.x += bih[j] + bhh[j]; a.y += bih[j + 64] + bhh[j + 64];
            a.z += bih[j + 128] + bhh[j + 128]; a.w += bih[j + 192] + bhh[j + 192];
            float ig = sigm_(a.x), fg = sigm_(a.y), gg = tanh2_(a.z), og = sigm_(a.w);
            c = fmaf(fg, c, ig * gg);
            h = og * tanh2_(c);
        }
        float last = fmaxf(h, 0.f);
        float acc = rc_val(xb[0]) + bcj;
#pragma unroll
        for (int k = 0; k < 64; ++k)
            acc = fmaf(__shfl(last, k), Wc[jm * 96 + 32 + k], acc);
        comb4 = fmaxf(acc, 0.f);
    } else {
        comb4 = fmaxf(rc_val(xb[0]) + bcj, 0.f);
    }
    float logit = bt[j];
    const float* wtr = Wt + j * 32;
#pragma unroll
    for (int k = 0; k < 32; ++k) logit = fmaf(__shfl(comb4, k), wtr[k], logit);
    float mx = logit;
#pragma unroll
    for (int off = 32; off; off >>= 1) mx = fmaxf(mx, __shfl_xor(mx, off));
    float ex = __expf(logit - mx);
    float sum = ex;
#pragma unroll
    for (int off = 32; off; off >>= 1) sum += __shfl_xor(sum, off);
    out[b * 64 + j] = logit - mx - __logf(sum);
}

extern "C" void kernel_launch(void* const* d_in, const int* in_sizes, int n_in,
                              void* d_out, int out_size, void* d_ws, size_t ws_size,
                              hipStream_t stream) {
    const int* x = (const int*)d_in[0];
    const int* s = (const int*)d_in[1];
    const float* emb = (const float*)d_in[2];
    const float* Wih = (const float*)d_in[3];
    const float* Whh = (const float*)d_in[4];
    const float* bih = (const float*)d_in[5];
    const float* bhh = (const float*)d_in[6];
    const float* h0 = (const float*)d_in[7];
    const float* c0 = (const float*)d_in[8];
    const float* Wc = (const float*)d_in[9];
    const float* bc = (const float*)d_in[10];
    const float* Wt = (const float*)d_in[11];
    const float* bt = (const float*)d_in[12];
    float* out = (float*)d_out;

    auto al16 = [](size_t v) { return (v + 15) & ~(size_t)15; };
    size_t off = 0;
    size_t oWpack = off; off = al16(off + (size_t)28672 * 2);  // WhhHi[256x72]+WihHi[256x40]
    size_t oWc1 = off;   off = al16(off + 1024 * 2);
    size_t oWc2 = off;   off = al16(off + 2048 * 2);
    size_t oWt = off;    off = al16(off + 2048 * 2);
    size_t oBsum = off;  off = al16(off + 256 * 4);
    size_t oEmbH = off;  off = al16(off + (size_t)NV * NE * 2);
    size_t oCH = off;    off = al16(off + 32 * 4);
    size_t oListH = off; off = al16(off + (size_t)NB * 4);
    size_t oListL = off; off = al16(off + (size_t)NB * 4);
    size_t need = off;

    char* ws = (char*)d_ws;
    if (ws_size >= need) {
        short* wpack = (short*)(ws + oWpack);
        short* wc1 = (short*)(ws + oWc1);
        short* wc2 = (short*)(ws + oWc2);
        short* wth = (short*)(ws + oWt);
        float* bsum = (float*)(ws + oBsum);
        short* embH = (short*)(ws + oEmbH);
        int* cHp = (int*)(ws + oCH);
        int* listH = (int*)(ws + oListH);
        int* listL = (int*)(ws + oListL);

        classify_prep<<<dim3(256), dim3(1024), 0, stream>>>(
            s, emb, Wih, Whh, bih, bhh, Wc, Wt,
            embH, wpack, wc1, wc2, wth, bsum, cHp, listH, listL);
        main_fused<<<dim3(768), dim3(256), 0, stream>>>(
            x, emb, h0, c0, Wc, bc, Wt, bt, bsum,
            wpack, wc1, wc2, wth, embH, cHp, listH, listL, out);
    } else {
        tagger_fallback<<<dim3(4096), dim3(512), 0, stream>>>(
            x, s, emb, Wih, Whh, bih, bhh, h0, c0, Wc, bc, Wt, bt, out);
    }
}